// Round 8
// baseline (8858.698 us; speedup 1.0000x reference)
//
#include <hip/hip_runtime.h>

// Persistent 2-layer LSTM, LAYER-SPLIT across 2 co-resident blocks/CU.
// Grid = 512 blocks: role = blockIdx&1 (0 = L1 chain, 1 = L2 chain),
// wg = blockIdx>>1 in [0,256): rb=wg>>5 (batch rows rb*32..+31),
// cg=wg&31 (hidden units cg*16..+15). The two recurrence chains
//   A: h1[t-1] -> h1[t]   (L1 blocks)
//   B: h1[u], h2[u-1] -> h2[u], out[u-1]  (L2 blocks)
// are coupled with slack (L2 u needs L1 u; L1 t needs L2 t-2 for buffer
// reuse) -> steady-state period = max(A,B) instead of the previous serial
// A+B (r6 measured A+B ~ 12.7us/tick, insensitive to VALU and barrier
// structure => latency-bound; concurrency is the remaining lever).
// Residency engineering: LDS ~75KB/block (2x75<160KB), launch_bounds(256,2)
// caps 256 VGPR (8 waves/CU). L2 keeps W_ih2 hi+lo in regs (128 VGPR) and
// STREAMS W_hh2 fp32 from its (XCD-L2-resident, 128KB/WG) slice with a
// 4-deep register prefetch, deriving fp16 hi/lo on the fly (fully unrolled,
// static indices). All exchange agent-scope LLC (proven baseline path).
// Bounded polls + dead-flag escape: a residency/deadlock failure completes
// garbage in <100ms -> clean failed verify with counters, never a hang.

#define WGS    512
#define NTHR   256
#define TSTEPS 512
#define HDIM   512
#define BATCH  256
#define FUT    8
#define NCOL   (TSTEPS + FUT)
#define HPLANE (BATCH * HDIM)   // one h plane (fp16 hi only)
#define FLAGSTRIDE 32           // u32s per flag line (128 B)
#define ROWB   1032             // LDS row pitch bytes (1024 + 8 pad)
#define GPITCH 68               // g-tile row pitch (floats)
#define POLLMAX 4000u           // poll bound (~1ms) then dead-escape
#define W_F1 0                  // flag word: L1 step counter (L1 role writes)
#define W_F2 4                  // flag word: L2 step counter (L2 role writes)
#define W_FO 8                  // flag word: future outfeed counter (L2 role)

typedef _Float16 half_t;
typedef _Float16 f16x8 __attribute__((ext_vector_type(8)));
typedef float    f32x4 __attribute__((ext_vector_type(4)));
typedef __attribute__((address_space(1))) const unsigned int gu32;
typedef __attribute__((address_space(3))) unsigned int su32;

struct Params {
  const float* input_t;
  const float* W_ih1; const float* b_ih1; const float* W_hh1; const float* b_hh1;
  const float* W_ih2; const float* b_ih2; const float* W_hh2; const float* b_hh2;
  const float* W_lin; const float* b_lin;
  float* out;
  unsigned* flags;     // [256][FLAGSTRIDE]
  float* outfeed;      // [BATCH]
  half_t* h1buf;   // [2 pp][BATCH][HDIM]
  half_t* h2buf;   // [2 pp][BATCH][HDIM]
};

// Fast exact transcendentals (validated r5/r6: absmax identical to libm).
__device__ __forceinline__ float sigm(float x) {
  const float e = __builtin_amdgcn_exp2f(-1.44269504f * x);
  return __builtin_amdgcn_rcpf(1.0f + e);
}
__device__ __forceinline__ float tanh_f(float x) {
  const float e = __builtin_amdgcn_exp2f(2.88539009f * x);
  return 1.0f - 2.0f * __builtin_amdgcn_rcpf(e + 1.0f);
}

// LLC-coherent volatile accessors (proven baseline path).
__device__ __forceinline__ f16x8 vload8(const half_t* p) {
  return *(const volatile f16x8*)p;
}
__device__ __forceinline__ void vstore2(half_t* p, half_t a, half_t b) {
  union { half_t h[2]; unsigned u; } x;
  x.h[0] = a; x.h[1] = b;
  *(volatile unsigned*)p = x.u;
}

// fp32 -> (hi, lo) fp16 fragments
__device__ __forceinline__ void split8(const float4 a, const float4 b,
                                       f16x8& hi, f16x8& lo) {
  float v[8] = {a.x, a.y, a.z, a.w, b.x, b.y, b.z, b.w};
#pragma unroll
  for (int i = 0; i < 8; ++i) {
    const half_t h = (half_t)v[i];
    hi[i] = h;
    lo[i] = (half_t)(v[i] - (float)h);
  }
}
__device__ __forceinline__ void load8_split(const float* p, f16x8& hi, f16x8& lo) {
  split8(*(const float4*)p, *(const float4*)(p + 4), hi, lo);
}

// Wait until all 32 lines of the row group reach target on `word`.
// Bounded; on timeout sets *dead_s so every later wait exits instantly ->
// a broken-residency run completes (wrong) in ~ms instead of hanging.
__device__ __forceinline__ void waitflag(unsigned* flags, int gbase, int word,
                                         int target, int* dead_s) {
  if (target <= 0) return;
  if (threadIdx.x < 32 && *dead_s == 0) {
    unsigned* fp = &flags[(gbase + threadIdx.x) * FLAGSTRIDE + word];
    unsigned iters = 0;
    while ((int)__hip_atomic_load(fp, __ATOMIC_RELAXED, __HIP_MEMORY_SCOPE_AGENT) < target) {
      __builtin_amdgcn_s_sleep(1);
      if (++iters > POLLMAX) { *dead_s = 1; break; }
    }
  }
  __syncthreads();
}
__device__ __forceinline__ void signalflag(unsigned* flags, int wg, int word,
                                           unsigned value) {
  __syncthreads();   // vmcnt(0) drain on every wave => prior stores at LLC
  if (threadIdx.x == 0)
    __hip_atomic_store(&flags[wg * FLAGSTRIDE + word], value,
                       __ATOMIC_RELAXED, __HIP_MEMORY_SCOPE_AGENT);
}

__global__ void __launch_bounds__(NTHR, 2) lstm_fused(Params P) {
  const int tid  = threadIdx.x;
  const int bid  = blockIdx.x;
  const int role = bid & 1;      // 0 = L1 chain, 1 = L2 chain
  const int wg   = bid >> 1;     // logical WG 0..255
  const int cg   = wg & 31;
  const int rb   = wg >> 5;
  const int gbase = wg & ~31;
  const int wv   = tid >> 6;
  const int lane = tid & 63;
  const int m    = lane & 15;
  const int quad = lane >> 4;

  __shared__ __align__(16) char ldsA1[32 * ROWB];  // 33 KB
  __shared__ __align__(16) char ldsA2[32 * ROWB];  // 33 KB (L2 role only)
  __shared__ float gs[32 * GPITCH];                // 8.7 KB gate pre-acts
  __shared__ float in_s[32];
  __shared__ float bias_s[64];
  __shared__ float w1x_s[64];
  __shared__ int dead_s;

  if (tid == 0) dead_s = 0;

  const int eb  = tid >> 3;
  const int eu0 = (tid & 7) * 2;
  const int gc  = wv * HDIM + cg * 16 + m;   // this lane's B column

  half_t* h1p[2] = {P.h1buf, P.h1buf + HPLANE};
  half_t* h2p[2] = {P.h2buf, P.h2buf + HPLANE};

  // Bulk async stage: 8 rows per wave (1024 B per instruction), LLC-coherent.
  auto stage = [&](const half_t* hp, char* ldst) {
#pragma unroll
    for (int r = 0; r < 8; ++r) {
      const int row = wv * 8 + r;
      const half_t* g = hp + (size_t)(rb * 32 + row) * HDIM + lane * 8;
      __builtin_amdgcn_global_load_lds((gu32*)g, (su32*)(ldst + row * ROWB), 16, 0, 0x11);
    }
  };
  // C/D layout: col = lane&15, row = rt*16 + quad*4 + reg.
  auto writeg = [&](f32x4* acc) {
#pragma unroll
    for (int rt = 0; rt < 2; ++rt)
#pragma unroll
      for (int rg = 0; rg < 4; ++rg)
        gs[(rt * 16 + quad * 4 + rg) * GPITCH + wv * 16 + m] = acc[rt][rg];
  };
  auto wf = [&](int word, int target) { waitflag(P.flags, gbase, word, target, &dead_s); };
  auto sig = [&](int word, unsigned v)  { signalflag(P.flags, wg, word, v); };

  const f32x4 z4 = {0.f, 0.f, 0.f, 0.f};

  if (role == 0) {
    // ==================== L1 chain ====================
    if (tid < 64) {
      const int gcp = (tid >> 4) * HDIM + cg * 16 + (tid & 15);
      bias_s[tid] = P.b_ih1[gcp] + P.b_hh1[gcp];
      w1x_s[tid]  = P.W_ih1[gcp];
    }
    if (tid < 32) in_s[tid] = P.input_t[rb * 32 + tid];

    f16x8 B1h[16], B1l[16];
    {
      const float* w1r = P.W_hh1 + (size_t)gc * HDIM;
#pragma unroll
      for (int kk = 0; kk < 16; ++kk)
        load8_split(w1r + kk * 32 + quad * 8, B1h[kk], B1l[kk]);
    }
    __syncthreads();

    float c1[2] = {0.f, 0.f};
    f32x4 acc[2];

    auto phase1 = [&]() {
      const char* ap = ldsA1 + m * ROWB + quad * 16;
#pragma unroll
      for (int kk = 0; kk < 16; ++kk) {
        const int o = kk * 64;
        const f16x8 a0 = *(const f16x8*)(ap + o);
        const f16x8 a1 = *(const f16x8*)(ap + 16 * ROWB + o);
        acc[0] = __builtin_amdgcn_mfma_f32_16x16x32_f16(a0, B1h[kk], acc[0], 0, 0, 0);
        acc[1] = __builtin_amdgcn_mfma_f32_16x16x32_f16(a1, B1h[kk], acc[1], 0, 0, 0);
        acc[0] = __builtin_amdgcn_mfma_f32_16x16x32_f16(a0, B1l[kk], acc[0], 0, 0, 0);
        acc[1] = __builtin_amdgcn_mfma_f32_16x16x32_f16(a1, B1l[kk], acc[1], 0, 0, 0);
      }
    };
    auto ew1 = [&](bool future, half_t* h1w) {
      const float xb = future ? *(volatile const float*)&P.outfeed[rb * 32 + eb] : in_s[eb];
      half_t hh[2];
#pragma unroll
      for (int uu = 0; uu < 2; ++uu) {
        const int u = eu0 + uu;
        const float ai = gs[eb * GPITCH + u]      + xb * w1x_s[u]      + bias_s[u];
        const float af = gs[eb * GPITCH + 16 + u] + xb * w1x_s[16 + u] + bias_s[16 + u];
        const float ag = gs[eb * GPITCH + 32 + u] + xb * w1x_s[32 + u] + bias_s[32 + u];
        const float ao = gs[eb * GPITCH + 48 + u] + xb * w1x_s[48 + u] + bias_s[48 + u];
        const float ig = sigm(ai), fg = sigm(af), gg = tanh_f(ag), og = sigm(ao);
        const float c = fg * c1[uu] + ig * gg;
        c1[uu] = c;
        hh[uu] = (half_t)(og * tanh_f(c));
      }
      vstore2(h1w + (size_t)(rb * 32 + eb) * HDIM + cg * 16 + eu0, hh[0], hh[1]);
    };

    // Main: L1 step t consumes h1[t-1] (plane (t+1)&1), produces h1[t] (plane t&1).
    // Overwrite safety: h1[t-2] consumers are L1 peers (F1>=t) and L2 step t-2 (F2>=t-1).
    for (int t = 0; t < TSTEPS; ++t) {
      wf(W_F1, t);
      wf(W_F2, t - 1);
      stage(h1p[(t + 1) & 1], ldsA1);
      __syncthreads();
      acc[0] = z4; acc[1] = z4;
      phase1();
      writeg(acc);
      __syncthreads();
      ew1(false, h1p[t & 1]);
      sig(W_F1, t + 1);
    }
    // Future: step s uses x = outfeed (gated FO) produced from h2[s-1].
    for (int k = 0; k < FUT; ++k) {
      const int s = TSTEPS + k;
      wf(W_FO, k + 1);
      wf(W_F1, s);
      stage(h1p[(s + 1) & 1], ldsA1);
      __syncthreads();
      acc[0] = z4; acc[1] = z4;
      phase1();
      writeg(acc);
      __syncthreads();
      ew1(true, h1p[s & 1]);
      sig(W_F1, s + 1);
    }
  } else {
    // ==================== L2 chain ====================
    if (tid < 64) {
      const int gcp = (tid >> 4) * HDIM + cg * 16 + (tid & 15);
      bias_s[tid] = P.b_ih2[gcp] + P.b_hh2[gcp];
    }
    f16x8 B2h[16], B2l[16];   // W_ih2 hi+lo (in regs)
    {
      const float* wi2r = P.W_ih2 + (size_t)gc * HDIM;
#pragma unroll
      for (int kk = 0; kk < 16; ++kk)
        load8_split(wi2r + kk * 32 + quad * 8, B2h[kk], B2l[kk]);
    }
    __syncthreads();

    const float* whr = P.W_hh2 + (size_t)gc * HDIM;   // streamed per tick
    float c2[2] = {0.f, 0.f};
    f32x4 acc[2];

    auto phase2 = [&]() {
      const char* ap = ldsA1 + m * ROWB + quad * 16;   // h1[u]
      const char* cp = ldsA2 + m * ROWB + quad * 16;   // h2[u-1]
      float4 pa[4], pb[4];
#pragma unroll
      for (int i = 0; i < 4; ++i) {
        pa[i] = *(const float4*)(whr + i * 32 + quad * 8);
        pb[i] = *(const float4*)(whr + i * 32 + quad * 8 + 4);
      }
#pragma unroll
      for (int kk = 0; kk < 16; ++kk) {
        const int o = kk * 64;
        const f16x8 a0 = *(const f16x8*)(ap + o);
        const f16x8 a1 = *(const f16x8*)(ap + 16 * ROWB + o);
        const f16x8 c0 = *(const f16x8*)(cp + o);
        const f16x8 c1r = *(const f16x8*)(cp + 16 * ROWB + o);
        acc[0] = __builtin_amdgcn_mfma_f32_16x16x32_f16(a0, B2h[kk], acc[0], 0, 0, 0);
        acc[1] = __builtin_amdgcn_mfma_f32_16x16x32_f16(a1, B2h[kk], acc[1], 0, 0, 0);
        acc[0] = __builtin_amdgcn_mfma_f32_16x16x32_f16(a0, B2l[kk], acc[0], 0, 0, 0);
        acc[1] = __builtin_amdgcn_mfma_f32_16x16x32_f16(a1, B2l[kk], acc[1], 0, 0, 0);
        f16x8 hh, hl;
        split8(pa[kk & 3], pb[kk & 3], hh, hl);   // static idx (full unroll)
        acc[0] = __builtin_amdgcn_mfma_f32_16x16x32_f16(c0,  hh, acc[0], 0, 0, 0);
        acc[1] = __builtin_amdgcn_mfma_f32_16x16x32_f16(c1r, hh, acc[1], 0, 0, 0);
        acc[0] = __builtin_amdgcn_mfma_f32_16x16x32_f16(c0,  hl, acc[0], 0, 0, 0);
        acc[1] = __builtin_amdgcn_mfma_f32_16x16x32_f16(c1r, hl, acc[1], 0, 0, 0);
        if (kk < 12) {
          pa[kk & 3] = *(const float4*)(whr + (kk + 4) * 32 + quad * 8);
          pb[kk & 3] = *(const float4*)(whr + (kk + 4) * 32 + quad * 8 + 4);
        }
      }
    };
    auto ew2 = [&](half_t* h2w) {
      half_t hh[2];
#pragma unroll
      for (int uu = 0; uu < 2; ++uu) {
        const int u = eu0 + uu;
        const float ai = gs[eb * GPITCH + u]      + bias_s[u];
        const float af = gs[eb * GPITCH + 16 + u] + bias_s[16 + u];
        const float ag = gs[eb * GPITCH + 32 + u] + bias_s[32 + u];
        const float ao = gs[eb * GPITCH + 48 + u] + bias_s[48 + u];
        const float ig = sigm(ai), fg = sigm(af), gg = tanh_f(ag), og = sigm(ao);
        const float c = fg * c2[uu] + ig * gg;
        c2[uu] = c;
        hh[uu] = (half_t)(og * tanh_f(c));
      }
      vstore2(h2w + (size_t)(rb * 32 + eb) * HDIM + cg * 16 + eu0, hh[0], hh[1]);
    };
    // outrow split: read pre-signal (data gated by F2), finish post-signal.
    auto outread = [&](const half_t* hp) {
      f16x8 hv = {};
      if (tid < 64) hv = vload8(hp + (size_t)wg * HDIM + lane * 8);
      return hv;
    };
    auto outfinish = [&](f16x8 hv, int col) {
      if (tid < 64) {
        const float4 wa = *(const float4*)(P.W_lin + lane * 8);
        const float4 wb = *(const float4*)(P.W_lin + lane * 8 + 4);
        float s = (float)hv[0]*wa.x + (float)hv[1]*wa.y + (float)hv[2]*wa.z + (float)hv[3]*wa.w
                + (float)hv[4]*wb.x + (float)hv[5]*wb.y + (float)hv[6]*wb.z + (float)hv[7]*wb.w;
#pragma unroll
        for (int off = 32; off > 0; off >>= 1) s += __shfl_down(s, off);
        if (lane == 0) {
          s += P.b_lin[0];
          P.out[(size_t)wg * NCOL + col] = s;
          *(volatile float*)&P.outfeed[wg] = s;
        }
      }
    };

    // Main: L2 step u consumes h1[u] (plane u&1, gated F1>=u+1) and h2[u-1]
    // (plane (u+1)&1, gated F2>=u); produces h2[u] (plane u&1) and out[u-1].
    for (int u = 0; u < TSTEPS; ++u) {
      wf(W_F2, u);
      stage(h2p[(u + 1) & 1], ldsA2);           // h2 available first: overlap F1 poll
      f16x8 hv = {};
      if (u >= 1) hv = outread(h2p[(u + 1) & 1]);  // h2[u-1] row (pre-signal-safe)
      wf(W_F1, u + 1);
      stage(h1p[u & 1], ldsA1);
      __syncthreads();
      acc[0] = z4; acc[1] = z4;
      phase2();
      writeg(acc);
      __syncthreads();
      ew2(h2p[u & 1]);
      sig(W_F2, u + 1);
      if (u >= 1) outfinish(hv, u - 1);          // off critical path
    }
    // Future steps.
    for (int k = 0; k < FUT; ++k) {
      const int s = TSTEPS + k;
      wf(W_F2, s);
      f16x8 hv = outread(h2p[(s + 1) & 1]);      // h2[s-1]
      outfinish(hv, s - 1);
      sig(W_FO, k + 1);                          // outfeed drained -> FO
      wf(W_F1, s + 1);                           // h1[s] ready
      stage(h1p[s & 1], ldsA1);
      stage(h2p[(s + 1) & 1], ldsA2);            // h2[s-1]
      __syncthreads();
      acc[0] = z4; acc[1] = z4;
      phase2();
      writeg(acc);
      __syncthreads();
      ew2(h2p[s & 1]);
      sig(W_F2, s + 1);
    }
    wf(W_F2, TSTEPS + FUT);
    f16x8 hv = outread(h2p[(TSTEPS + FUT + 1) & 1]);   // h2[519] (plane 1)
    outfinish(hv, TSTEPS + FUT - 1);
  }
}

extern "C" void kernel_launch(void* const* d_in, const int* in_sizes, int n_in,
                              void* d_out, int out_size, void* d_ws, size_t ws_size,
                              hipStream_t stream) {
  Params P;
  P.input_t = (const float*)d_in[0];
  // d_in[1] = y : only its shape (T) matters; T hardcoded 512
  P.W_ih1 = (const float*)d_in[2];  P.b_ih1 = (const float*)d_in[3];
  P.W_hh1 = (const float*)d_in[4];  P.b_hh1 = (const float*)d_in[5];
  P.W_ih2 = (const float*)d_in[6];  P.b_ih2 = (const float*)d_in[7];
  P.W_hh2 = (const float*)d_in[8];  P.b_hh2 = (const float*)d_in[9];
  P.W_lin = (const float*)d_in[10]; P.b_lin = (const float*)d_in[11];
  P.out   = (float*)d_out;

  char* ws = (char*)d_ws;
  P.outfeed = (float*)(ws + 256);                  // 1 KB
  P.flags   = (unsigned*)(ws + 4096);              // 32 KB (F1/F2/FO words per line)
  P.h1buf   = (half_t*)(ws + 4096 + 32768);        // [2][B][H] fp16 = 512 KB
  P.h2buf   = (half_t*)(ws + 4096 + 32768 + 2 * (size_t)HPLANE * sizeof(half_t));
  const size_t need = 4096 + 32768 + 4 * (size_t)HPLANE * sizeof(half_t);  // ~1.1 MB

  (void)hipMemsetAsync(d_ws, 0, need, stream);  // zero flags+outfeed+h buffers

  // 512 blocks, 2/CU (LDS ~75KB, <=256 VGPR via launch_bounds) => all resident.
  lstm_fused<<<dim3(WGS), dim3(NTHR), 0, stream>>>(P);
}